// Round 1
// baseline (148.931 us; speedup 1.0000x reference)
//
#include <hip/hip_runtime.h>
#include <math.h>

#define IN_UNITS 1152
#define OUT_UNITS 32
#define BATCH 64
#define NCHK 18            // i-chunks per batch
#define IPB 64             // i's per block (1152/18)
#define IGROUP 8           // i's per thread-group pass (256 thr = 8 i x 32 o)
#define NG (IPB/IGROUP)    // 8 loop iterations
#define PREC 33            // partial record floats per (block,o): S, mu[16], v2[16]
#define PBLK (OUT_UNITS*PREC)

// thread layout: t = il*32 + o  (o = lane&31, il = t>>5)
// wave = 2 i's x 32 o; softmax over o = shfl_xor within 32-lane half.
template<int MODE>   // 0 = it0 stats only, 1 = R-update + next-iter stats
__global__ __launch_bounds__(256) void caps_main(
    const float* __restrict__ a_in, const float* __restrict__ Mm,
    const float* __restrict__ Wt,
    const float* __restrict__ mu_g, const float* __restrict__ i2v_g,
    const float* __restrict__ lae_g,
    float* __restrict__ part)
{
    const int t = threadIdx.x;
    const int o = t & 31;
    const int il = t >> 5;
    const int wv = t >> 6;
    const int lane = t & 63;
    const int b = blockIdx.y;
    const int c = blockIdx.x;
    const int i0 = c * IPB;

    __shared__ float sM[IGROUP*16];
    __shared__ float sA[IGROUP];
    __shared__ float sMu[16*32];   // [ch][o]
    __shared__ float sI2[16*32];   // [ch][o]
    __shared__ float sLae[32];
    __shared__ float sRed[4][PBLK];

    if (MODE == 1) {
        for (int idx = t; idx < 512; idx += 256) {
            sMu[idx] = mu_g[b*512 + idx];
            sI2[idx] = i2v_g[b*512 + idx];
        }
        if (t < 32) sLae[t] = lae_g[b*32 + t];
    }

    float pS = 0.f, pmu[16], pv2[16];
    #pragma unroll
    for (int k = 0; k < 16; ++k) { pmu[k] = 0.f; pv2[k] = 0.f; }

    for (int g = 0; g < NG; ++g) {
        __syncthreads();
        const int ibase = i0 + g*IGROUP;
        if (t < IGROUP*16) sM[t] = Mm[(size_t)(b*IN_UNITS + ibase)*16 + t];
        if (t < IGROUP)    sA[t] = a_in[b*IN_UNITS + ibase + t];
        __syncthreads();

        const int i = ibase + il;
        float w[16];
        const float4* wp = (const float4*)(Wt + ((size_t)i*OUT_UNITS + o)*16);
        *(float4*)&w[0]  = wp[0];
        *(float4*)&w[4]  = wp[1];
        *(float4*)&w[8]  = wp[2];
        *(float4*)&w[12] = wp[3];

        float v[16];
        #pragma unroll
        for (int x = 0; x < 4; ++x) {
            #pragma unroll
            for (int z = 0; z < 4; ++z) {
                float acc = 0.f;
                #pragma unroll
                for (int y = 0; y < 4; ++y)
                    acc = fmaf(sM[il*16 + x*4 + y], w[y*4 + z], acc);
                v[x*4 + z] = acc;
            }
        }

        float wgt;
        if (MODE == 0) {
            wgt = sA[il] * (1.0f/32.0f);   // R0 = 1/32, times input_a
        } else {
            float ex = 0.f;
            #pragma unroll
            for (int k = 0; k < 16; ++k) {
                float d = v[k] - sMu[k*32 + o];
                ex = fmaf(d*d, sI2[k*32 + o], ex);
            }
            float logit = sLae[o] - ex;     // log a + log eff + exponent
            float mx = logit;
            #pragma unroll
            for (int m = 16; m >= 1; m >>= 1) mx = fmaxf(mx, __shfl_xor(mx, m));
            float e = __expf(logit - mx);
            float s = e;
            #pragma unroll
            for (int m = 16; m >= 1; m >>= 1) s += __shfl_xor(s, m);
            float R = e / s;                // normalized over o
            wgt = R * sA[il];               // next iter: R *= input_a
        }

        pS += wgt;
        #pragma unroll
        for (int k = 0; k < 16; ++k) {
            pmu[k] = fmaf(wgt, v[k], pmu[k]);
            pv2[k] = fmaf(wgt*v[k], v[k], pv2[k]);
        }
    }

    // combine the two i's of each wave (lanes l <-> l^32, same o)
    pS += __shfl_xor(pS, 32);
    #pragma unroll
    for (int k = 0; k < 16; ++k) {
        pmu[k] += __shfl_xor(pmu[k], 32);
        pv2[k] += __shfl_xor(pv2[k], 32);
    }
    __syncthreads();
    if (lane < 32) {
        sRed[wv][o*PREC + 0] = pS;
        #pragma unroll
        for (int k = 0; k < 16; ++k) {
            sRed[wv][o*PREC + 1  + k] = pmu[k];
            sRed[wv][o*PREC + 17 + k] = pv2[k];
        }
    }
    __syncthreads();
    float* dst = part + (size_t)(b*NCHK + c)*PBLK;
    for (int idx = t; idx < PBLK; idx += 256)
        dst[idx] = sRed[0][idx] + sRed[1][idx] + sRed[2][idx] + sRed[3][idx];
}

__global__ __launch_bounds__(256) void caps_fin(
    const float* __restrict__ part,
    const float* __restrict__ beta_u, const float* __restrict__ beta_a,
    float* __restrict__ mu_g, float* __restrict__ i2v_g, float* __restrict__ lae_g,
    float lamb, float* __restrict__ out)
{
    const int tid = blockIdx.x*blockDim.x + threadIdx.x;
    if (tid >= BATCH*OUT_UNITS) return;
    const int b = tid >> 5, o = tid & 31;

    float S = 0.f, m[16], q[16];
    #pragma unroll
    for (int k = 0; k < 16; ++k) { m[k] = 0.f; q[k] = 0.f; }
    for (int c = 0; c < NCHK; ++c) {
        const float* p = part + (size_t)(b*NCHK + c)*PBLK + o*PREC;
        S += p[0];
        #pragma unroll
        for (int k = 0; k < 16; ++k) { m[k] += p[1+k]; q[k] += p[17+k]; }
    }

    const float invS = 1.f / S;
    float mu[16], var[16], logvarsum = 0.f;
    #pragma unroll
    for (int k = 0; k < 16; ++k) {
        mu[k] = m[k] * invS;
        float vv = q[k]*invS - mu[k]*mu[k];   // E[v^2] - mu^2
        vv = fmaxf(vv, 1e-30f);
        var[k] = vv;
        logvarsum += logf(vv);
    }
    // cost_sum = sum_R * (16*beta_u + sum_ch log sigma);  log sigma = 0.5 log var
    const float cost = S * (16.f*beta_u[o] + 0.5f*logvarsum);
    const float x = lamb * (beta_a[o] - cost);
    const float log_a = (x >= 0.f) ? -log1pf(expf(-x)) : (x - log1pf(expf(x)));
    const float LOG2PI = 1.8378770664093453f;
    const float logeff = 16.f*LOG2PI + logvarsum;   // log prod(2 pi var)

    lae_g[tid] = log_a + logeff;
    #pragma unroll
    for (int k = 0; k < 16; ++k) {
        mu_g[b*512 + k*32 + o]  = mu[k];        // transposed [b][ch][o]
        i2v_g[b*512 + k*32 + o] = 0.5f / var[k];
    }
    if (out) {
        out[tid] = 1.f / (1.f + expf(-x));                      // a (64,32)
        #pragma unroll
        for (int k = 0; k < 16; ++k)
            out[BATCH*OUT_UNITS + (size_t)tid*16 + k] = mu[k];  // mu (64,32,16)
    }
}

extern "C" void kernel_launch(void* const* d_in, const int* in_sizes, int n_in,
                              void* d_out, int out_size, void* d_ws, size_t ws_size,
                              hipStream_t stream)
{
    const float* a_in = (const float*)d_in[0];
    const float* Mm   = (const float*)d_in[1];
    const float* Wt   = (const float*)d_in[2];
    const float* bu   = (const float*)d_in[3];
    const float* ba   = (const float*)d_in[4];
    float* out = (float*)d_out;

    char* ws = (char*)d_ws;
    size_t off = 0;
    float* part  = (float*)(ws + off); off += (size_t)BATCH*NCHK*PBLK*sizeof(float);
    float* mu_g  = (float*)(ws + off); off += (size_t)BATCH*512*sizeof(float);
    float* i2v_g = (float*)(ws + off); off += (size_t)BATCH*512*sizeof(float);
    float* lae_g = (float*)(ws + off); off += (size_t)BATCH*32*sizeof(float);

    dim3 grid(NCHK, BATCH), blk(256);
    // it 0: stats under R = input_a/32
    caps_main<0><<<grid, blk, 0, stream>>>(a_in, Mm, Wt, nullptr, nullptr, nullptr, part);
    caps_fin<<<8, 256, 0, stream>>>(part, bu, ba, mu_g, i2v_g, lae_g, 0.01f, nullptr);
    // it 0 R-update + it 1 stats
    caps_main<1><<<grid, blk, 0, stream>>>(a_in, Mm, Wt, mu_g, i2v_g, lae_g, part);
    caps_fin<<<8, 256, 0, stream>>>(part, bu, ba, mu_g, i2v_g, lae_g, 0.012f, nullptr);
    // it 1 R-update + it 2 stats
    caps_main<1><<<grid, blk, 0, stream>>>(a_in, Mm, Wt, mu_g, i2v_g, lae_g, part);
    caps_fin<<<8, 256, 0, stream>>>(part, bu, ba, mu_g, i2v_g, lae_g, 0.0144f, out);
}

// Round 2
// 132.706 us; speedup vs baseline: 1.1223x; 1.1223x over previous
//
#include <hip/hip_runtime.h>
#include <math.h>

#define IN_UNITS 1152
#define OUT_UNITS 32
#define BATCH 64
#define NCHK 36            // i-chunks per batch pair
#define IPB 32             // i's per block (1152/36)
#define IGROUP 8           // i's per pass (256 thr = 8 i x 32 o)
#define NG (IPB/IGROUP)    // 4
#define B2 2               // batches per block (W regs reused across both)
#define PREC 33            // floats per (chunk,o): S, mu[16], v2[16]
#define PBLK (OUT_UNITS*PREC)   // 1056

// thread layout: t = il*32 + o  (o = t&31, il = t>>5 in 0..7)
// lanes l and l^32 of a wave: same o, adjacent il -> combine via shfl_xor(32).
template<int MODE>   // 0 = it0 stats only, 1 = R-update + next-iter stats
__global__ __launch_bounds__(256) void caps_main(
    const float* __restrict__ a_in, const float* __restrict__ Mm,
    const float* __restrict__ Wt,
    const float* __restrict__ mu_g, const float* __restrict__ i2v_g,
    const float* __restrict__ lae_g,
    float* __restrict__ part)
{
    const int t  = threadIdx.x;
    const int o  = t & 31;
    const int il = t >> 5;
    const int wv = t >> 6;
    const int lane = t & 63;
    const int b0 = blockIdx.y * B2;
    const int c  = blockIdx.x;
    const int i0 = c * IPB;

    __shared__ float sMu[B2][512];
    __shared__ float sI2[B2][512];
    __shared__ float sLae[B2][32];
    __shared__ float sRed[2][B2*PBLK];

    if (MODE == 1) {
        for (int idx = t; idx < B2*512; idx += 256) {
            int bb = idx >> 9, r = idx & 511;
            sMu[bb][r] = mu_g[(size_t)(b0+bb)*512 + r];
            sI2[bb][r] = i2v_g[(size_t)(b0+bb)*512 + r];
        }
        if (t < B2*32) sLae[t>>5][t&31] = lae_g[b0*32 + t];
        __syncthreads();
    }

    float pS[B2], pmu[B2][16], pv2[B2][16];
    #pragma unroll
    for (int bb = 0; bb < B2; ++bb) {
        pS[bb] = 0.f;
        #pragma unroll
        for (int k = 0; k < 16; ++k) { pmu[bb][k] = 0.f; pv2[bb][k] = 0.f; }
    }

    const float4* wp0 = (const float4*)(Wt + ((size_t)(i0+il)*OUT_UNITS + o)*16);

    #pragma unroll
    for (int g = 0; g < NG; ++g) {
        const int i = i0 + g*IGROUP + il;
        // W row for this (i,o): 64B, coalesced across o. Reused for both b.
        float w[16];
        const float4* wp = wp0 + (size_t)g*IGROUP*OUT_UNITS*4;
        *(float4*)&w[0]  = wp[0];
        *(float4*)&w[4]  = wp[1];
        *(float4*)&w[8]  = wp[2];
        *(float4*)&w[12] = wp[3];

        #pragma unroll
        for (int bb = 0; bb < B2; ++bb) {
            const int b = b0 + bb;
            // M row: 64B read by 32 lanes (same il) -> L1 broadcast, no LDS needed
            float Mr[16];
            const float4* mp = (const float4*)(Mm + ((size_t)b*IN_UNITS + i)*16);
            *(float4*)&Mr[0]  = mp[0];
            *(float4*)&Mr[4]  = mp[1];
            *(float4*)&Mr[8]  = mp[2];
            *(float4*)&Mr[12] = mp[3];
            const float a_val = a_in[(size_t)b*IN_UNITS + i];

            float v[16];
            #pragma unroll
            for (int x = 0; x < 4; ++x) {
                #pragma unroll
                for (int z = 0; z < 4; ++z) {
                    float acc = 0.f;
                    #pragma unroll
                    for (int y = 0; y < 4; ++y)
                        acc = fmaf(Mr[x*4 + y], w[y*4 + z], acc);
                    v[x*4 + z] = acc;
                }
            }

            float wgt;
            if (MODE == 0) {
                wgt = a_val * (1.0f/32.0f);         // R0 = 1/32
            } else {
                float ex = 0.f;
                #pragma unroll
                for (int k = 0; k < 16; ++k) {
                    float d = v[k] - sMu[bb][k*32 + o];
                    ex = fmaf(d*d, sI2[bb][k*32 + o], ex);
                }
                float logit = sLae[bb][o] - ex;      // log a + log eff + exponent
                float mx = logit;
                #pragma unroll
                for (int m = 16; m >= 1; m >>= 1) mx = fmaxf(mx, __shfl_xor(mx, m));
                float e = __expf(logit - mx);
                float s = e;
                #pragma unroll
                for (int m = 16; m >= 1; m >>= 1) s += __shfl_xor(s, m);
                wgt = (e / s) * a_val;               // R normalized over o, * input_a
            }

            pS[bb] += wgt;
            #pragma unroll
            for (int k = 0; k < 16; ++k) {
                pmu[bb][k] = fmaf(wgt, v[k], pmu[bb][k]);
                pv2[bb][k] = fmaf(wgt*v[k], v[k], pv2[bb][k]);
            }
        }
    }

    // combine the two il's of each wave (lanes l <-> l^32 share o)
    #pragma unroll
    for (int bb = 0; bb < B2; ++bb) {
        pS[bb] += __shfl_xor(pS[bb], 32);
        #pragma unroll
        for (int k = 0; k < 16; ++k) {
            pmu[bb][k] += __shfl_xor(pmu[bb][k], 32);
            pv2[bb][k] += __shfl_xor(pv2[bb][k], 32);
        }
    }
    __syncthreads();   // MODE1: done with sMu/sI2; all: before cross-wave reduce
    if (wv >= 2 && lane < 32) {
        #pragma unroll
        for (int bb = 0; bb < B2; ++bb) {
            sRed[wv-2][bb*PBLK + o*PREC + 0] = pS[bb];
            #pragma unroll
            for (int k = 0; k < 16; ++k) {
                sRed[wv-2][bb*PBLK + o*PREC + 1  + k] = pmu[bb][k];
                sRed[wv-2][bb*PBLK + o*PREC + 17 + k] = pv2[bb][k];
            }
        }
    }
    __syncthreads();
    if (wv < 2 && lane < 32) {
        #pragma unroll
        for (int bb = 0; bb < B2; ++bb) {
            float* r = &sRed[wv][bb*PBLK + o*PREC];
            r[0] += pS[bb];
            #pragma unroll
            for (int k = 0; k < 16; ++k) {
                r[1  + k] += pmu[bb][k];
                r[17 + k] += pv2[bb][k];
            }
        }
    }
    __syncthreads();
    for (int idx = t; idx < B2*PBLK; idx += 256) {
        int bb = (idx >= PBLK);
        int r  = idx - bb*PBLK;
        part[((size_t)(b0+bb)*NCHK + c)*PBLK + r] = sRed[0][idx] + sRed[1][idx];
    }
}

// one block per b; 8 segments x 32 o; segments split the chunk reduction
__global__ __launch_bounds__(256) void caps_fin(
    const float* __restrict__ part,
    const float* __restrict__ beta_u, const float* __restrict__ beta_a,
    float* __restrict__ mu_g, float* __restrict__ i2v_g, float* __restrict__ lae_g,
    float lamb, float* __restrict__ out)
{
    const int b = blockIdx.x;
    const int t = threadIdx.x;
    const int o = t & 31;
    const int seg = t >> 5;

    float S = 0.f, m[16], q[16];
    #pragma unroll
    for (int k = 0; k < 16; ++k) { m[k] = 0.f; q[k] = 0.f; }
    for (int c = seg; c < NCHK; c += 8) {
        const float* p = part + ((size_t)b*NCHK + c)*PBLK + o*PREC;
        S += p[0];
        #pragma unroll
        for (int k = 0; k < 16; ++k) { m[k] += p[1+k]; q[k] += p[17+k]; }
    }

    __shared__ float sF[8][PBLK];
    {
        float* r = &sF[seg][o*PREC];
        r[0] = S;
        #pragma unroll
        for (int k = 0; k < 16; ++k) { r[1+k] = m[k]; r[17+k] = q[k]; }
    }
    __syncthreads();
    if (t < 32) {
        #pragma unroll
        for (int s = 1; s < 8; ++s) {
            const float* r = &sF[s][o*PREC];
            S += r[0];
            #pragma unroll
            for (int k = 0; k < 16; ++k) { m[k] += r[1+k]; q[k] += r[17+k]; }
        }

        const float invS = 1.f / S;
        float mu[16], var[16], logvarsum = 0.f;
        #pragma unroll
        for (int k = 0; k < 16; ++k) {
            mu[k] = m[k] * invS;
            float vv = q[k]*invS - mu[k]*mu[k];   // E[v^2] - mu^2
            vv = fmaxf(vv, 1e-30f);
            var[k] = vv;
            logvarsum += logf(vv);
        }
        const float cost = S * (16.f*beta_u[o] + 0.5f*logvarsum);
        const float x = lamb * (beta_a[o] - cost);
        const float log_a = (x >= 0.f) ? -log1pf(expf(-x)) : (x - log1pf(expf(x)));
        const float LOG2PI = 1.8378770664093453f;
        const float logeff = 16.f*LOG2PI + logvarsum;

        const int tid = b*32 + o;
        lae_g[tid] = log_a + logeff;
        #pragma unroll
        for (int k = 0; k < 16; ++k) {
            mu_g[(size_t)b*512 + k*32 + o]  = mu[k];      // [b][ch][o]
            i2v_g[(size_t)b*512 + k*32 + o] = 0.5f / var[k];
        }
        if (out) {
            out[tid] = 1.f / (1.f + expf(-x));                      // a (64,32)
            #pragma unroll
            for (int k = 0; k < 16; ++k)
                out[BATCH*OUT_UNITS + (size_t)tid*16 + k] = mu[k];  // mu (64,32,16)
        }
    }
}

extern "C" void kernel_launch(void* const* d_in, const int* in_sizes, int n_in,
                              void* d_out, int out_size, void* d_ws, size_t ws_size,
                              hipStream_t stream)
{
    const float* a_in = (const float*)d_in[0];
    const float* Mm   = (const float*)d_in[1];
    const float* Wt   = (const float*)d_in[2];
    const float* bu   = (const float*)d_in[3];
    const float* ba   = (const float*)d_in[4];
    float* out = (float*)d_out;

    char* ws = (char*)d_ws;
    size_t off = 0;
    float* part  = (float*)(ws + off); off += (size_t)BATCH*NCHK*PBLK*sizeof(float);
    float* mu_g  = (float*)(ws + off); off += (size_t)BATCH*512*sizeof(float);
    float* i2v_g = (float*)(ws + off); off += (size_t)BATCH*512*sizeof(float);
    float* lae_g = (float*)(ws + off); off += (size_t)BATCH*32*sizeof(float);

    dim3 grid(NCHK, BATCH/B2), blk(256);
    // it 0: stats under R = input_a/32
    caps_main<0><<<grid, blk, 0, stream>>>(a_in, Mm, Wt, nullptr, nullptr, nullptr, part);
    caps_fin<<<BATCH, 256, 0, stream>>>(part, bu, ba, mu_g, i2v_g, lae_g, 0.01f, nullptr);
    // it 0 R-update + it 1 stats
    caps_main<1><<<grid, blk, 0, stream>>>(a_in, Mm, Wt, mu_g, i2v_g, lae_g, part);
    caps_fin<<<BATCH, 256, 0, stream>>>(part, bu, ba, mu_g, i2v_g, lae_g, 0.012f, nullptr);
    // it 1 R-update + it 2 stats
    caps_main<1><<<grid, blk, 0, stream>>>(a_in, Mm, Wt, mu_g, i2v_g, lae_g, part);
    caps_fin<<<BATCH, 256, 0, stream>>>(part, bu, ba, mu_g, i2v_g, lae_g, 0.0144f, out);
}

// Round 3
// 110.353 us; speedup vs baseline: 1.3496x; 1.2026x over previous
//
#include <hip/hip_runtime.h>
#include <math.h>

#define IN_UNITS 1152
#define OUT_UNITS 32
#define BATCH 64
#define NCHK 48            // i-chunks; 48%8==0 -> chunk c maps to XCD c%8
#define IPB 24             // i's per block
#define IGROUP 8           // i's per pass (256 thr = 8 i x 32 o)
#define NG 3               // IPB/IGROUP
#define PREC 33            // floats per (chunk,o): S, mu[16], v2[16]
#define PBLK (OUT_UNITS*PREC)   // 1056

// W[i][o][ch] -> Wt[i][y][o][z]  (ch = y*4+z) so the 4 per-y float4 loads are
// lane-contiguous (512B per instruction) instead of 64B-strided.
__global__ __launch_bounds__(256) void w_transpose(
    const float* __restrict__ W, float* __restrict__ Wt)
{
    const int gid = blockIdx.x*256 + threadIdx.x;   // 1152*512 total
    const int i = gid >> 9, r = gid & 511, o = r >> 4, ch = r & 15;
    Wt[((i*4 + (ch>>2))*32 + o)*4 + (ch&3)] = W[gid];
}

// thread layout: t = il*32 + o  (o = t&31, il = t>>5 in 0..7)
// lanes l and l^32 of a wave share o -> combine via shfl_xor(32).
template<int MODE>   // 0 = it0 stats only, 1 = R-update + next-iter stats
__global__ __launch_bounds__(256, 4) void caps_main(
    const float* __restrict__ a_in, const float* __restrict__ Mm,
    const float4* __restrict__ Wt4,
    const float* __restrict__ mu_g, const float* __restrict__ i2v_g,
    const float* __restrict__ lae_g,
    float* __restrict__ part)
{
    const int t  = threadIdx.x;
    const int o  = t & 31;
    const int il = t >> 5;
    const int wv = t >> 6;
    const int lane = t & 63;
    const int b = blockIdx.y;
    const int c = blockIdx.x;
    const int i0 = c * IPB;

    __shared__ float sMu[MODE ? 512 : 1];
    __shared__ float sI2[MODE ? 512 : 1];
    __shared__ float sLae[MODE ? 32 : 1];
    __shared__ float sRed[2][PBLK];

    if (MODE) {
        for (int idx = t; idx < 512; idx += 256) {
            sMu[idx] = mu_g[b*512 + idx];
            sI2[idx] = i2v_g[b*512 + idx];
        }
        if (t < 32) sLae[t] = lae_g[b*32 + t];
        __syncthreads();
    }

    float pS = 0.f, pmu[16], pv2[16];
    #pragma unroll
    for (int k = 0; k < 16; ++k) { pmu[k] = 0.f; pv2[k] = 0.f; }

    #pragma unroll
    for (int g = 0; g < NG; ++g) {
        const int i = i0 + g*IGROUP + il;

        float w[16];
        #pragma unroll
        for (int y = 0; y < 4; ++y)
            *(float4*)&w[y*4] = Wt4[(i*4 + y)*32 + o];   // coalesced 512B/inst

        float Mr[16];   // 64B row, broadcast to 32 lanes (same il) via L1
        const float4* mp = (const float4*)Mm + (b*IN_UNITS + i)*4;
        *(float4*)&Mr[0]  = mp[0];
        *(float4*)&Mr[4]  = mp[1];
        *(float4*)&Mr[8]  = mp[2];
        *(float4*)&Mr[12] = mp[3];
        const float a_val = a_in[b*IN_UNITS + i];

        float v[16];
        #pragma unroll
        for (int x = 0; x < 4; ++x) {
            #pragma unroll
            for (int z = 0; z < 4; ++z) {
                float acc = 0.f;
                #pragma unroll
                for (int y = 0; y < 4; ++y)
                    acc = fmaf(Mr[x*4 + y], w[y*4 + z], acc);
                v[x*4 + z] = acc;
            }
        }

        float wgt;
        if (MODE == 0) {
            wgt = a_val * (1.0f/32.0f);          // R0 = 1/32
        } else {
            float ex0 = 0.f, ex1 = 0.f;          // two chains for ILP
            #pragma unroll
            for (int k = 0; k < 16; k += 2) {
                float d0 = v[k]   - sMu[k*32 + o];
                float d1 = v[k+1] - sMu[(k+1)*32 + o];
                ex0 = fmaf(d0*d0, sI2[k*32 + o], ex0);
                ex1 = fmaf(d1*d1, sI2[(k+1)*32 + o], ex1);
            }
            float logit = sLae[o] - (ex0 + ex1);  // log a + log eff + exponent
            float mx = logit;
            #pragma unroll
            for (int m = 16; m >= 1; m >>= 1) mx = fmaxf(mx, __shfl_xor(mx, m));
            float e = __expf(logit - mx);
            float s = e;
            #pragma unroll
            for (int m = 16; m >= 1; m >>= 1) s += __shfl_xor(s, m);
            wgt = (e / s) * a_val;                // R normalized over o, * input_a
        }

        pS += wgt;
        #pragma unroll
        for (int k = 0; k < 16; ++k) {
            pmu[k] = fmaf(wgt, v[k], pmu[k]);
            pv2[k] = fmaf(wgt*v[k], v[k], pv2[k]);
        }
    }

    // combine the two il's of each wave (lanes l <-> l^32 share o)
    pS += __shfl_xor(pS, 32);
    #pragma unroll
    for (int k = 0; k < 16; ++k) {
        pmu[k] += __shfl_xor(pmu[k], 32);
        pv2[k] += __shfl_xor(pv2[k], 32);
    }
    __syncthreads();   // MODE1: done with sMu/sI2 reads
    if (wv >= 2 && lane < 32) {
        float* r = &sRed[wv-2][o*PREC];
        r[0] = pS;
        #pragma unroll
        for (int k = 0; k < 16; ++k) { r[1+k] = pmu[k]; r[17+k] = pv2[k]; }
    }
    __syncthreads();
    if (wv < 2 && lane < 32) {
        float* r = &sRed[wv][o*PREC];
        r[0] += pS;
        #pragma unroll
        for (int k = 0; k < 16; ++k) { r[1+k] += pmu[k]; r[17+k] += pv2[k]; }
    }
    __syncthreads();
    float* dst = part + ((size_t)b*NCHK + c)*PBLK;
    for (int idx = t; idx < PBLK; idx += 256)
        dst[idx] = sRed[0][idx] + sRed[1][idx];
}

// one block per b; 8 segments x 32 o; segments split the chunk reduction
__global__ __launch_bounds__(256) void caps_fin(
    const float* __restrict__ part,
    const float* __restrict__ beta_u, const float* __restrict__ beta_a,
    float* __restrict__ mu_g, float* __restrict__ i2v_g, float* __restrict__ lae_g,
    float lamb, float* __restrict__ out)
{
    const int b = blockIdx.x;
    const int t = threadIdx.x;
    const int o = t & 31;
    const int seg = t >> 5;

    float S = 0.f, m[16], q[16];
    #pragma unroll
    for (int k = 0; k < 16; ++k) { m[k] = 0.f; q[k] = 0.f; }
    for (int c = seg; c < NCHK; c += 8) {
        const float* p = part + ((size_t)b*NCHK + c)*PBLK + o*PREC;
        S += p[0];
        #pragma unroll
        for (int k = 0; k < 16; ++k) { m[k] += p[1+k]; q[k] += p[17+k]; }
    }

    __shared__ float sF[8][PBLK];
    {
        float* r = &sF[seg][o*PREC];
        r[0] = S;
        #pragma unroll
        for (int k = 0; k < 16; ++k) { r[1+k] = m[k]; r[17+k] = q[k]; }
    }
    __syncthreads();
    if (t < 32) {
        #pragma unroll
        for (int s = 1; s < 8; ++s) {
            const float* r = &sF[s][o*PREC];
            S += r[0];
            #pragma unroll
            for (int k = 0; k < 16; ++k) { m[k] += r[1+k]; q[k] += r[17+k]; }
        }

        const float invS = 1.f / S;
        float mu[16], var[16], logvarsum = 0.f;
        #pragma unroll
        for (int k = 0; k < 16; ++k) {
            mu[k] = m[k] * invS;
            float vv = q[k]*invS - mu[k]*mu[k];   // E[v^2] - mu^2
            vv = fmaxf(vv, 1e-30f);
            var[k] = vv;
            logvarsum += logf(vv);
        }
        const float cost = S * (16.f*beta_u[o] + 0.5f*logvarsum);
        const float x = lamb * (beta_a[o] - cost);
        const float log_a = (x >= 0.f) ? -log1pf(expf(-x)) : (x - log1pf(expf(x)));
        const float LOG2PI = 1.8378770664093453f;
        const float logeff = 16.f*LOG2PI + logvarsum;

        const int tid = b*32 + o;
        lae_g[tid] = log_a + logeff;
        #pragma unroll
        for (int k = 0; k < 16; ++k) {
            mu_g[(size_t)b*512 + k*32 + o]  = mu[k];      // [b][ch][o]
            i2v_g[(size_t)b*512 + k*32 + o] = 0.5f / var[k];
        }
        if (out) {
            out[tid] = 1.f / (1.f + expf(-x));                      // a (64,32)
            #pragma unroll
            for (int k = 0; k < 16; ++k)
                out[BATCH*OUT_UNITS + (size_t)tid*16 + k] = mu[k];  // mu (64,32,16)
        }
    }
}

extern "C" void kernel_launch(void* const* d_in, const int* in_sizes, int n_in,
                              void* d_out, int out_size, void* d_ws, size_t ws_size,
                              hipStream_t stream)
{
    const float* a_in = (const float*)d_in[0];
    const float* Mm   = (const float*)d_in[1];
    const float* Wg   = (const float*)d_in[2];
    const float* bu   = (const float*)d_in[3];
    const float* ba   = (const float*)d_in[4];
    float* out = (float*)d_out;

    char* ws = (char*)d_ws;
    size_t off = 0;
    float* part  = (float*)(ws + off); off += (size_t)BATCH*NCHK*PBLK*sizeof(float);
    float* mu_g  = (float*)(ws + off); off += (size_t)BATCH*512*sizeof(float);
    float* i2v_g = (float*)(ws + off); off += (size_t)BATCH*512*sizeof(float);
    float* lae_g = (float*)(ws + off); off += (size_t)BATCH*32*sizeof(float);
    float* Wt    = (float*)(ws + off); off += (size_t)IN_UNITS*OUT_UNITS*16*sizeof(float);

    w_transpose<<<IN_UNITS*512/256, 256, 0, stream>>>(Wg, Wt);

    dim3 grid(NCHK, BATCH), blk(256);
    const float4* Wt4 = (const float4*)Wt;
    // it 0: stats under R = input_a/32
    caps_main<0><<<grid, blk, 0, stream>>>(a_in, Mm, Wt4, nullptr, nullptr, nullptr, part);
    caps_fin<<<BATCH, 256, 0, stream>>>(part, bu, ba, mu_g, i2v_g, lae_g, 0.01f, nullptr);
    // it 0 R-update + it 1 stats
    caps_main<1><<<grid, blk, 0, stream>>>(a_in, Mm, Wt4, mu_g, i2v_g, lae_g, part);
    caps_fin<<<BATCH, 256, 0, stream>>>(part, bu, ba, mu_g, i2v_g, lae_g, 0.012f, nullptr);
    // it 1 R-update + it 2 stats
    caps_main<1><<<grid, blk, 0, stream>>>(a_in, Mm, Wt4, mu_g, i2v_g, lae_g, part);
    caps_fin<<<BATCH, 256, 0, stream>>>(part, bu, ba, mu_g, i2v_g, lae_g, 0.0144f, out);
}